// Round 4
// baseline (204.576 us; speedup 1.0000x reference)
//
#include <hip/hip_runtime.h>
#include <cstdint>
#include <cstddef>

#define NV 6
#define ND 256
#define NHEAD 8
#define NBEV 80
#define NQ 6400
#define NTOK 7441
#define MROWS (NV * NTOK)
#define FEPS 1e-5f

// value GEMM tiling
#define VROWT 698                 // ceil(MROWS/64)
#define VBLKS (VROWT * 2)         // 1396
#define OABLKS 300                // (6400/64) * 3
#define GBLKS (VBLKS + OABLKS)    // 1696, % 8 == 0
#define GCHUNK (GBLKS / 8)        // 212

typedef __attribute__((ext_vector_type(8))) short bfx8;
typedef __attribute__((ext_vector_type(4))) float fx4;
typedef __attribute__((ext_vector_type(4))) _Float16 hx4;
typedef __attribute__((ext_vector_type(4))) unsigned short usx4;

__device__ __forceinline__ unsigned short f2bf(float x) {
    uint32_t u = __builtin_bit_cast(uint32_t, x);
    u += 0x7FFFu + ((u >> 16) & 1u);
    return (unsigned short)(u >> 16);
}
__device__ __forceinline__ float lof(uint32_t u) {
    return __builtin_bit_cast(float, u << 16);
}
__device__ __forceinline__ float hif(uint32_t u) {
    return __builtin_bit_cast(float, u & 0xFFFF0000u);
}

// ---------------------------------------------------------------------------
// K_prep (flat grid 1070 x 256):
//   [0,150)      proj coords/mask per (v,q)
//   [150,406)    vWt  = bf16(vW^T)    (coalesced reads, strided stores)
//   [406,662)    oaWt[0:256)   from oW
//   [662,790)    oaWt[256:384) from aW
//   [790,1046)   outWt = bf16(outW^T)
//   [1046,1070)  emb_proj[v*4+l][c] = (ve[v]+le[l]) @ vW + vB
// ---------------------------------------------------------------------------
__global__ __launch_bounds__(256) void k_prep(
        const float* __restrict__ l2i, const float* __restrict__ ve,
        const float* __restrict__ le, const float* __restrict__ vW,
        const float* __restrict__ vB, const float* __restrict__ oW,
        const float* __restrict__ aW, const float* __restrict__ outW,
        float2* __restrict__ coords, int* __restrict__ mask,
        unsigned short* __restrict__ vWt, unsigned short* __restrict__ oaWt,
        unsigned short* __restrict__ outWt, float* __restrict__ emb_proj) {
    int bid = blockIdx.x;
    int t = threadIdx.x;
    if (bid < 150) {
        int idx = bid * 256 + t;
        int v = idx / NQ, q = idx - v * NQ;
        float xs = ((float)(q % NBEV) + 0.5f) / (float)NBEV;
        float ys = ((float)(q / NBEV) + 0.5f) / (float)NBEV;
        float x = xs * 96.0f - 48.0f;
        float y = ys * 96.0f - 48.0f;
        float z = x * 8.0f - 5.0f;  // faithful ref bug
        const float* M = l2i + v * 16;
        float ip0 = M[0] * x + M[1] * y + M[2] * z + M[3];
        float ip1 = M[4] * x + M[5] * y + M[6] * z + M[7];
        float ip2 = M[8] * x + M[9] * y + M[10] * z + M[11];
        float dz = fmaxf(ip2, FEPS);
        float xn = ip0 / dz / 800.0f;
        float yn = ip1 / dz / 448.0f;
        bool m = (ip2 > FEPS) && (xn > 0.0f) && (xn < 1.0f) && (yn > 0.0f) && (yn < 1.0f);
        coords[idx] = make_float2(xn, yn);
        mask[idx] = m ? 1 : 0;
    } else if (bid < 406) {
        int e = (bid - 150) * 256 + t;
        int k = e >> 8, n = e & 255;          // read coalesced in n
        vWt[(size_t)n * 256 + k] = f2bf(vW[(size_t)k * 256 + n]);
    } else if (bid < 662) {
        int e = (bid - 406) * 256 + t;
        int k = e >> 8, n = e & 255;
        oaWt[(size_t)n * 256 + k] = f2bf(oW[(size_t)k * 256 + n]);
    } else if (bid < 790) {
        int e = (bid - 662) * 256 + t;
        int k = e >> 7, n = e & 127;
        oaWt[(size_t)(256 + n) * 256 + k] = f2bf(aW[(size_t)k * 128 + n]);
    } else if (bid < 1046) {
        int e = (bid - 790) * 256 + t;
        int k = e >> 8, n = e & 255;
        outWt[(size_t)n * 256 + k] = f2bf(outW[(size_t)k * 256 + n]);
    } else {
        int blk = bid - 1046;  // v*4 + l
        int v = blk >> 2, l = blk & 3;
        float acc = vB[t];
        for (int d = 0; d < ND; ++d)
            acc += (ve[v * ND + d] + le[l * ND + d]) * vW[d * ND + t];
        emb_proj[blk * ND + t] = acc;
    }
}

// ---------------------------------------------------------------------------
// K_gemms (flat 1696 blocks, XCD-chunk swizzled):
//   lb in [0,1396): value GEMM, BM=64 x BN=128 tile; row-tile = lb>>1,
//                   c-tile = lb&1 (paired tiles share A rows -> same XCD).
//   lb in [1396,1696): [off|aw] GEMM, A = bev, N = 384 concat, BM=64.
// 4 waves as 2x2; per wave 32x64 -> acc frags 2x4 of 16x16x32 bf16 MFMA.
// ---------------------------------------------------------------------------
__global__ __launch_bounds__(256) void k_gemms(
        const float* __restrict__ f0, const float* __restrict__ f1,
        const float* __restrict__ f2, const float* __restrict__ f3,
        const unsigned short* __restrict__ vWt, const float* __restrict__ emb_proj,
        unsigned short* __restrict__ value,
        const float* __restrict__ bev, const unsigned short* __restrict__ oaWt,
        const float* __restrict__ oB, const float* __restrict__ aB,
        float* __restrict__ off, float* __restrict__ aw_pre) {
    __shared__ unsigned short As[64][40];
    __shared__ unsigned short Bs[128][40];
    __shared__ const float* rowptr[64];
    __shared__ int rowstride[64];
    __shared__ int rowemb[64];
    int b = blockIdx.x;
    int lb = (b & 7) * GCHUNK + (b >> 3);    // chunked XCD swizzle (bijective)
    int t = threadIdx.x;
    int lane = t & 63, w = t >> 6;
    int wm = w >> 1, wn = w & 1;
    int lr = lane & 15, lk = lane >> 4;
    int mA = t & 63, kg = t >> 6;

    fx4 acc[2][4];
#pragma unroll
    for (int i = 0; i < 2; ++i)
#pragma unroll
        for (int j = 0; j < 4; ++j) acc[i][j] = (fx4)0.0f;

    if (lb < VBLKS) {
        // ---------------- value GEMM ----------------
        int m0 = (lb >> 1) * 64, c0 = (lb & 1) * 128;
        if (t < 64) {
            int m = m0 + t;
            if (m >= MROWS) m = MROWS - 1;
            int v = m / NTOK, n = m - v * NTOK;
            int l, p, hw;
            const float* base;
            if (n < 5600)      { l = 0; p = n;        hw = 5600; base = f0; }
            else if (n < 7000) { l = 1; p = n - 5600; hw = 1400; base = f1; }
            else if (n < 7350) { l = 2; p = n - 7000; hw = 350;  base = f2; }
            else               { l = 3; p = n - 7350; hw = 91;   base = f3; }
            rowptr[t] = base + (size_t)v * ND * hw + p;
            rowstride[t] = hw;
            rowemb[t] = v * 4 + l;
        }
        __syncthreads();
        const unsigned short* bp = vWt + (size_t)(c0 + (t >> 1)) * 256 + (t & 1) * 16;
        const float* rp = rowptr[mA];
        int rs = rowstride[mA];
        for (int k0 = 0; k0 < 256; k0 += 32) {
            float va[8];
#pragma unroll
            for (int i = 0; i < 8; ++i)
                va[i] = rp[(size_t)(k0 + kg * 8 + i) * rs];
            bfx8 a8;
#pragma unroll
            for (int i = 0; i < 8; ++i) a8[i] = (short)f2bf(va[i]);
            *(bfx8*)&As[mA][kg * 8] = a8;
            *(bfx8*)&Bs[t >> 1][(t & 1) * 16] = *(const bfx8*)(bp + k0);
            *(bfx8*)&Bs[t >> 1][(t & 1) * 16 + 8] = *(const bfx8*)(bp + k0 + 8);
            __syncthreads();
            bfx8 af[2], bf[4];
#pragma unroll
            for (int f = 0; f < 2; ++f)
                af[f] = *(bfx8*)&As[wm * 32 + f * 16 + lr][lk * 8];
#pragma unroll
            for (int f = 0; f < 4; ++f)
                bf[f] = *(bfx8*)&Bs[wn * 64 + f * 16 + lr][lk * 8];
#pragma unroll
            for (int fm = 0; fm < 2; ++fm)
#pragma unroll
                for (int fn = 0; fn < 4; ++fn)
                    acc[fm][fn] = __builtin_amdgcn_mfma_f32_16x16x32_bf16(
                        af[fm], bf[fn], acc[fm][fn], 0, 0, 0);
            __syncthreads();
        }
#pragma unroll
        for (int fm = 0; fm < 2; ++fm) {
#pragma unroll
            for (int fn = 0; fn < 4; ++fn) {
                int col = c0 + wn * 64 + fn * 16 + lr;
#pragma unroll
                for (int r = 0; r < 4; ++r) {
                    int rl = wm * 32 + fm * 16 + lk * 4 + r;
                    int m = m0 + rl;
                    if (m < MROWS) {
                        float e = emb_proj[(size_t)rowemb[rl] * ND + col];
                        value[(size_t)m * ND + col] = f2bf(acc[fm][fn][r] + e);
                    }
                }
            }
        }
    } else {
        // ---------------- off/aw GEMM ----------------
        int r6 = lb - VBLKS;                  // 100 x 3
        int m0 = (r6 / 3) * 64, c0 = (r6 % 3) * 128;
        const float* ap = bev + (size_t)(m0 + mA) * 256 + kg * 8;
        const unsigned short* bp = oaWt + (size_t)(c0 + (t >> 1)) * 256 + (t & 1) * 16;
        for (int k0 = 0; k0 < 256; k0 += 32) {
            float va[8];
            *(float4*)&va[0] = *(const float4*)(ap + k0);
            *(float4*)&va[4] = *(const float4*)(ap + k0 + 4);
            bfx8 a8;
#pragma unroll
            for (int i = 0; i < 8; ++i) a8[i] = (short)f2bf(va[i]);
            *(bfx8*)&As[mA][kg * 8] = a8;
            *(bfx8*)&Bs[t >> 1][(t & 1) * 16] = *(const bfx8*)(bp + k0);
            *(bfx8*)&Bs[t >> 1][(t & 1) * 16 + 8] = *(const bfx8*)(bp + k0 + 8);
            __syncthreads();
            bfx8 af[2], bf[4];
#pragma unroll
            for (int f = 0; f < 2; ++f)
                af[f] = *(bfx8*)&As[wm * 32 + f * 16 + lr][lk * 8];
#pragma unroll
            for (int f = 0; f < 4; ++f)
                bf[f] = *(bfx8*)&Bs[wn * 64 + f * 16 + lr][lk * 8];
#pragma unroll
            for (int fm = 0; fm < 2; ++fm)
#pragma unroll
                for (int fn = 0; fn < 4; ++fn)
                    acc[fm][fn] = __builtin_amdgcn_mfma_f32_16x16x32_bf16(
                        af[fm], bf[fn], acc[fm][fn], 0, 0, 0);
            __syncthreads();
        }
        if (c0 < 256) {
#pragma unroll
            for (int fm = 0; fm < 2; ++fm) {
#pragma unroll
                for (int fn = 0; fn < 4; ++fn) {
                    int col = c0 + wn * 64 + fn * 16 + lr;
                    float bs = oB[col];
#pragma unroll
                    for (int r = 0; r < 4; ++r) {
                        int m = m0 + wm * 32 + fm * 16 + lk * 4 + r;
                        off[(size_t)m * 256 + col] = acc[fm][fn][r] + bs;
                    }
                }
            }
        } else {
#pragma unroll
            for (int fm = 0; fm < 2; ++fm) {
#pragma unroll
                for (int fn = 0; fn < 4; ++fn) {
                    int col = wn * 64 + fn * 16 + lr;  // 0..127 within aw
                    float bs = aB[col];
#pragma unroll
                    for (int r = 0; r < 4; ++r) {
                        int m = m0 + wm * 32 + fm * 16 + lk * 4 + r;
                        aw_pre[(size_t)m * 128 + col] = acc[fm][fn][r] + bs;
                    }
                }
            }
        }
    }
}

// ---------------------------------------------------------------------------
// K_sample: 2 queries/block (thread = qq x channel-pair). Prologue: softmax +
// per-(q,v,combo) clamped token indices (ushort4) & aw-premultiplied bilinear
// weights (half4) into LDS (~26 KB). Main loop per (v,combo): 2 x 8B LDS
// broadcast + 4 coalesced dword loads + 8 FMA. XCD-chunked block swizzle.
// ---------------------------------------------------------------------------
#define SQB 2
__global__ __launch_bounds__(256) void k_sample(
        const float2* __restrict__ coords, const int* __restrict__ mask,
        const float* __restrict__ off, const float* __restrict__ awlog,
        const unsigned short* __restrict__ value, float* __restrict__ slots) {
    __shared__ float aw_s[SQB][128];
    __shared__ unsigned short lin_s[SQB][NV][128][4];
    __shared__ _Float16 w_s[SQB][NV][128][4];
    __shared__ float2 cxy_s[SQB][NV];
    __shared__ int msk_s[SQB][NV];

    int b = blockIdx.x;                       // 3200, % 8 == 0
    int lb = (b & 7) * (NQ / SQB / 8) + (b >> 3);
    int q0 = lb * SQB;
    int t = threadIdx.x;
    if (t < SQB * NV) {
        int qq = t / NV, v = t - qq * NV;
        msk_s[qq][v] = mask[v * NQ + q0 + qq];
        cxy_s[qq][v] = coords[v * NQ + q0 + qq];
    }
    {
        int qq = t >> 7, c2 = t & 127;
        aw_s[qq][c2] = awlog[(size_t)(q0 + qq) * 128 + c2];
    }
    __syncthreads();
    if (t < SQB * NHEAD) {
        int qq = t >> 3, h = t & 7;
        float* p = &aw_s[qq][h * 16];
        float mx = p[0];
#pragma unroll
        for (int i = 1; i < 16; ++i) mx = fmaxf(mx, p[i]);
        float e[16];
        float s = 0.0f;
#pragma unroll
        for (int i = 0; i < 16; ++i) { e[i] = __expf(p[i] - mx); s += e[i]; }
        float inv = 1.0f / s;
#pragma unroll
        for (int i = 0; i < 16; ++i) p[i] = e[i] * inv;
    }
    __syncthreads();

    const int LW[4] = {100, 50, 25, 13};
    const int LH[4] = {56, 28, 14, 7};
    const int LST[4] = {0, 5600, 7000, 7350};
    for (int idx = t; idx < SQB * NV * 128; idx += 256) {
        int c2 = idx & 127;
        int rem = idx >> 7;
        int qq = rem / NV, v = rem - qq * NV;
        if (!msk_s[qq][v]) continue;
        int ll = (c2 >> 2) & 3;
        int iwl = LW[ll], ihl = LH[ll], st = LST[ll];
        float wl = (float)iwl, hl = (float)ihl;
        float2 o2 = *(const float2*)&off[(size_t)(q0 + qq) * 256 + 2 * c2];
        float2 cc = cxy_s[qq][v];
        float gx = cc.x * wl + o2.x - 0.5f;
        float gy = cc.y * hl + o2.y - 0.5f;
        float fxf = floorf(gx), fyf = floorf(gy);
        int x0 = (int)fxf, y0 = (int)fyf;
        float wx = gx - fxf, wy = gy - fyf;
        bool bx0 = (unsigned)x0 < (unsigned)iwl;
        bool bx1 = (unsigned)(x0 + 1) < (unsigned)iwl;
        bool by0 = (unsigned)y0 < (unsigned)ihl;
        bool by1 = (unsigned)(y0 + 1) < (unsigned)ihl;
        int cx0 = min(max(x0, 0), iwl - 1);
        int cx1 = min(max(x0 + 1, 0), iwl - 1);
        int cy0 = min(max(y0, 0), ihl - 1);
        int cy1 = min(max(y0 + 1, 0), ihl - 1);
        float wa = aw_s[qq][c2];
        int r0 = st + cy0 * iwl, r1 = st + cy1 * iwl;
        usx4 lin;
        lin.x = (unsigned short)(r0 + cx0);
        lin.y = (unsigned short)(r0 + cx1);
        lin.z = (unsigned short)(r1 + cx0);
        lin.w = (unsigned short)(r1 + cx1);
        hx4 ww;
        ww.x = (_Float16)((bx0 && by0) ? (1.0f - wx) * (1.0f - wy) * wa : 0.0f);
        ww.y = (_Float16)((bx1 && by0) ? wx * (1.0f - wy) * wa : 0.0f);
        ww.z = (_Float16)((bx0 && by1) ? (1.0f - wx) * wy * wa : 0.0f);
        ww.w = (_Float16)((bx1 && by1) ? wx * wy * wa : 0.0f);
        *(usx4*)lin_s[qq][v][c2] = lin;
        *(hx4*)w_s[qq][v][c2] = ww;
    }
    __syncthreads();

    int qq = t >> 7, cp = t & 127;
    int hb = (cp >> 4) * 16;
    float acc0 = 0.0f, acc1 = 0.0f;
    int cnt = 0;
#pragma unroll
    for (int v = 0; v < NV; ++v) cnt += msk_s[qq][v];
    for (int v = 0; v < NV; ++v) {
        if (!msk_s[qq][v]) continue;
        const uint32_t* vb = (const uint32_t*)(value + (size_t)v * NTOK * 256) + cp;
#pragma unroll
        for (int ci = 0; ci < 16; ++ci) {
            int c2 = hb + ci;
            usx4 lin = *(const usx4*)lin_s[qq][v][c2];
            hx4 wh = *(const hx4*)w_s[qq][v][c2];
            uint32_t u0 = vb[(size_t)lin.x * 128];
            uint32_t u1 = vb[(size_t)lin.y * 128];
            uint32_t u2 = vb[(size_t)lin.z * 128];
            uint32_t u3 = vb[(size_t)lin.w * 128];
            float w0 = (float)wh.x, w1 = (float)wh.y;
            float w2 = (float)wh.z, w3 = (float)wh.w;
            acc0 += w0 * lof(u0) + w1 * lof(u1) + w2 * lof(u2) + w3 * lof(u3);
            acc1 += w0 * hif(u0) + w1 * hif(u1) + w2 * hif(u2) + w3 * hif(u3);
        }
    }
    float invc = 1.0f / fmaxf((float)cnt, 1.0f);
    *(float2*)&slots[(size_t)(q0 + qq) * 256 + 2 * cp] = make_float2(acc0 * invc, acc1 * invc);
}

// ---------------------------------------------------------------------------
// K_out: out = slots @ outWt^T + outB + bev.  BM=64 x BN=128 MFMA tile.
// ---------------------------------------------------------------------------
__global__ __launch_bounds__(256) void k_out(
        const float* __restrict__ A, const unsigned short* __restrict__ Bt,
        const float* __restrict__ bias, const float* __restrict__ addsrc,
        float* __restrict__ out) {
    __shared__ unsigned short As[64][40];
    __shared__ unsigned short Bs[128][40];
    int t = threadIdx.x;
    int m0 = blockIdx.x * 64, c0 = blockIdx.y * 128;
    int lane = t & 63, w = t >> 6;
    int wm = w >> 1, wn = w & 1;
    int lr = lane & 15, lk = lane >> 4;
    int mA = t & 63, kg = t >> 6;
    const float* ap = A + (size_t)(m0 + mA) * 256 + kg * 8;
    const unsigned short* bp = Bt + (size_t)(c0 + (t >> 1)) * 256 + (t & 1) * 16;
    fx4 acc[2][4];
#pragma unroll
    for (int i = 0; i < 2; ++i)
#pragma unroll
        for (int j = 0; j < 4; ++j) acc[i][j] = (fx4)0.0f;
    for (int k0 = 0; k0 < 256; k0 += 32) {
        float va[8];
        *(float4*)&va[0] = *(const float4*)(ap + k0);
        *(float4*)&va[4] = *(const float4*)(ap + k0 + 4);
        bfx8 a8;
#pragma unroll
        for (int i = 0; i < 8; ++i) a8[i] = (short)f2bf(va[i]);
        *(bfx8*)&As[mA][kg * 8] = a8;
        *(bfx8*)&Bs[t >> 1][(t & 1) * 16] = *(const bfx8*)(bp + k0);
        *(bfx8*)&Bs[t >> 1][(t & 1) * 16 + 8] = *(const bfx8*)(bp + k0 + 8);
        __syncthreads();
        bfx8 af[2], bf[4];
#pragma unroll
        for (int f = 0; f < 2; ++f)
            af[f] = *(bfx8*)&As[wm * 32 + f * 16 + lr][lk * 8];
#pragma unroll
        for (int f = 0; f < 4; ++f)
            bf[f] = *(bfx8*)&Bs[wn * 64 + f * 16 + lr][lk * 8];
#pragma unroll
        for (int fm = 0; fm < 2; ++fm)
#pragma unroll
            for (int fn = 0; fn < 4; ++fn)
                acc[fm][fn] = __builtin_amdgcn_mfma_f32_16x16x32_bf16(
                    af[fm], bf[fn], acc[fm][fn], 0, 0, 0);
        __syncthreads();
    }
#pragma unroll
    for (int fm = 0; fm < 2; ++fm) {
#pragma unroll
        for (int fn = 0; fn < 4; ++fn) {
            int col = c0 + wn * 64 + fn * 16 + lr;
            float bs = bias[col];
#pragma unroll
            for (int r = 0; r < 4; ++r) {
                int m = m0 + wm * 32 + fm * 16 + lk * 4 + r;
                out[(size_t)m * 256 + col] =
                    acc[fm][fn][r] + bs + addsrc[(size_t)m * 256 + col];
            }
        }
    }
}

// ---------------------------------------------------------------------------
extern "C" void kernel_launch(void* const* d_in, const int* in_sizes, int n_in,
                              void* d_out, int out_size, void* d_ws, size_t ws_size,
                              hipStream_t stream) {
    const float* f0   = (const float*)d_in[0];
    const float* f1   = (const float*)d_in[1];
    const float* f2   = (const float*)d_in[2];
    const float* f3   = (const float*)d_in[3];
    const float* l2i  = (const float*)d_in[4];
    const float* bev  = (const float*)d_in[5];
    const float* le   = (const float*)d_in[6];
    const float* ve   = (const float*)d_in[7];
    const float* vW   = (const float*)d_in[8];
    const float* vB   = (const float*)d_in[9];
    const float* oW   = (const float*)d_in[10];
    const float* oB   = (const float*)d_in[11];
    const float* aW   = (const float*)d_in[12];
    const float* aB   = (const float*)d_in[13];
    const float* outW = (const float*)d_in[14];
    const float* outB = (const float*)d_in[15];
    float* out = (float*)d_out;

    char* ws = (char*)d_ws;
    size_t o = 0;
    auto alloc = [&](size_t bytes) {
        void* p = ws + o;
        o += (bytes + 255) & ~(size_t)255;
        return p;
    };
    float2* coords   = (float2*)alloc((size_t)NV * NQ * sizeof(float2));
    int*    mask     = (int*)alloc((size_t)NV * NQ * sizeof(int));
    float*  emb_proj = (float*)alloc((size_t)24 * ND * sizeof(float));
    float*  off      = (float*)alloc((size_t)NQ * 256 * sizeof(float));
    float*  aw_pre   = (float*)alloc((size_t)NQ * 128 * sizeof(float));
    float*  slots    = (float*)alloc((size_t)NQ * 256 * sizeof(float));
    unsigned short* value = (unsigned short*)alloc((size_t)MROWS * ND * sizeof(short));
    unsigned short* vWt   = (unsigned short*)alloc((size_t)256 * 256 * sizeof(short));
    unsigned short* oaWt  = (unsigned short*)alloc((size_t)384 * 256 * sizeof(short));
    unsigned short* outWt = (unsigned short*)alloc((size_t)256 * 256 * sizeof(short));

    k_prep<<<1070, 256, 0, stream>>>(l2i, ve, le, vW, vB, oW, aW, outW,
                                     coords, mask, vWt, oaWt, outWt, emb_proj);
    k_gemms<<<GBLKS, 256, 0, stream>>>(f0, f1, f2, f3, vWt, emb_proj, value,
                                       bev, oaWt, oB, aB, off, aw_pre);
    k_sample<<<NQ / SQB, 256, 0, stream>>>(coords, mask, off, aw_pre, value, slots);
    dim3 gout(NQ / 64, 2);
    k_out<<<gout, 256, 0, stream>>>(slots, outWt, outB, bev, out);
}

// Round 5
// 186.699 us; speedup vs baseline: 1.0958x; 1.0958x over previous
//
#include <hip/hip_runtime.h>
#include <cstdint>
#include <cstddef>

#define NV 6
#define ND 256
#define NHEAD 8
#define NBEV 80
#define NQ 6400
#define NTOK 7441
#define MROWS (NV * NTOK)
#define MROWSP 44672              // 349 * 128, padded row count for featT
#define FEPS 1e-5f

// k_gemms grid: 349*2 value tiles + 50*3 off/aw tiles
#define VBLKS 698
#define GBLKS 848                 // % 8 == 0
#define GCHUNK (GBLKS / 8)

// k_prep flat ranges
#define PR_PROJ 150
#define PR_TR   2832              // 6 v * 118 m-tiles * 4 k-tiles
#define PR_BEV  800
#define PB0 PR_PROJ
#define PB1 (PB0 + PR_TR)         // 2982
#define PB2 (PB1 + PR_BEV)        // 3782
#define PB3 (PB2 + 256)           // vWt     -> 4038
#define PB4 (PB3 + 256)           // oaWt oW -> 4294
#define PB5 (PB4 + 128)           // oaWt aW -> 4422
#define PB6 (PB5 + 256)           // outWt   -> 4678
#define PBT (PB6 + 24)            // emb_proj-> 4702

typedef __attribute__((ext_vector_type(8))) short bfx8;
typedef __attribute__((ext_vector_type(4))) float fx4;
typedef __attribute__((ext_vector_type(4))) _Float16 hx4;
typedef __attribute__((ext_vector_type(4))) unsigned short usx4;

__device__ __forceinline__ unsigned short f2bf(float x) {
    uint32_t u = __builtin_bit_cast(uint32_t, x);
    u += 0x7FFFu + ((u >> 16) & 1u);
    return (unsigned short)(u >> 16);
}
__device__ __forceinline__ float lof(uint32_t u) {
    return __builtin_bit_cast(float, u << 16);
}
__device__ __forceinline__ float hif(uint32_t u) {
    return __builtin_bit_cast(float, u & 0xFFFF0000u);
}

// ---------------------------------------------------------------------------
// K_prep (flat 4702 x 256): proj | featT transpose | bevh | weight transposes
// | emb_proj.  featT[v*NTOK+tok][k] bf16 built from channels-first feats via
// LDS 64x64 tile transpose (coalesced both sides).
// ---------------------------------------------------------------------------
__global__ __launch_bounds__(256) void k_prep(
        const float* __restrict__ f0, const float* __restrict__ f1,
        const float* __restrict__ f2, const float* __restrict__ f3,
        const float* __restrict__ l2i, const float* __restrict__ bev,
        const float* __restrict__ ve, const float* __restrict__ le,
        const float* __restrict__ vW, const float* __restrict__ vB,
        const float* __restrict__ oW, const float* __restrict__ aW,
        const float* __restrict__ outW,
        float2* __restrict__ coords, int* __restrict__ mask,
        unsigned short* __restrict__ featT, unsigned short* __restrict__ bevh,
        unsigned short* __restrict__ vWt, unsigned short* __restrict__ oaWt,
        unsigned short* __restrict__ outWt, float* __restrict__ emb_proj) {
    int bid = blockIdx.x;
    int t = threadIdx.x;
    if (bid < PB0) {
        int idx = bid * 256 + t;
        int v = idx / NQ, q = idx - v * NQ;
        float xs = ((float)(q % NBEV) + 0.5f) / (float)NBEV;
        float ys = ((float)(q / NBEV) + 0.5f) / (float)NBEV;
        float x = xs * 96.0f - 48.0f;
        float y = ys * 96.0f - 48.0f;
        float z = x * 8.0f - 5.0f;  // faithful ref bug
        const float* M = l2i + v * 16;
        float ip0 = M[0] * x + M[1] * y + M[2] * z + M[3];
        float ip1 = M[4] * x + M[5] * y + M[6] * z + M[7];
        float ip2 = M[8] * x + M[9] * y + M[10] * z + M[11];
        float dz = fmaxf(ip2, FEPS);
        float xn = ip0 / dz / 800.0f;
        float yn = ip1 / dz / 448.0f;
        bool m = (ip2 > FEPS) && (xn > 0.0f) && (xn < 1.0f) && (yn > 0.0f) && (yn < 1.0f);
        coords[idx] = make_float2(xn, yn);
        mask[idx] = m ? 1 : 0;
    } else if (bid < PB1) {
        // ---- featT transpose: 64x64 tile via LDS ----
        __shared__ float T[64][65];
        int idx = bid - PB0;
        int v = idx / 472;
        int rem = idx - v * 472;
        int mt = rem >> 2, kt = rem & 3;
        int hw, p0, st;
        const float* base;
        if (mt < 88)       { base = f0; hw = 5600; st = 0;    p0 = mt * 64; }
        else if (mt < 110) { base = f1; hw = 1400; st = 5600; p0 = (mt - 88) * 64; }
        else if (mt < 116) { base = f2; hw = 350;  st = 7000; p0 = (mt - 110) * 64; }
        else               { base = f3; hw = 91;   st = 7350; p0 = (mt - 116) * 64; }
        int k0 = kt * 64;
        const float* src = base + (size_t)v * 256 * hw;
#pragma unroll
        for (int i = 0; i < 16; ++i) {
            int ii = t + i * 256;
            int kk = ii >> 6, mm = ii & 63;
            float val = (p0 + mm < hw) ? src[(size_t)(k0 + kk) * hw + p0 + mm] : 0.0f;
            T[kk][mm] = val;
        }
        __syncthreads();
#pragma unroll
        for (int i = 0; i < 16; ++i) {
            int ii = t + i * 256;
            int mm = ii >> 6, kk = ii & 63;
            if (p0 + mm < hw)
                featT[(size_t)(v * NTOK + st + p0 + mm) * 256 + k0 + kk] = f2bf(T[kk][mm]);
        }
    } else if (bid < PB2) {
        size_t e = (size_t)(bid - PB1) * 2048 + t * 8;
        float4 a = *(const float4*)(bev + e);
        float4 b = *(const float4*)(bev + e + 4);
        bfx8 o;
        o[0] = (short)f2bf(a.x); o[1] = (short)f2bf(a.y);
        o[2] = (short)f2bf(a.z); o[3] = (short)f2bf(a.w);
        o[4] = (short)f2bf(b.x); o[5] = (short)f2bf(b.y);
        o[6] = (short)f2bf(b.z); o[7] = (short)f2bf(b.w);
        *(bfx8*)(bevh + e) = o;
    } else if (bid < PB3) {
        int e = (bid - PB2) * 256 + t;
        int k = e >> 8, n = e & 255;
        vWt[(size_t)n * 256 + k] = f2bf(vW[(size_t)k * 256 + n]);
    } else if (bid < PB4) {
        int e = (bid - PB3) * 256 + t;
        int k = e >> 8, n = e & 255;
        oaWt[(size_t)n * 256 + k] = f2bf(oW[(size_t)k * 256 + n]);
    } else if (bid < PB5) {
        int e = (bid - PB4) * 256 + t;
        int k = e >> 7, n = e & 127;
        oaWt[(size_t)(256 + n) * 256 + k] = f2bf(aW[(size_t)k * 128 + n]);
    } else if (bid < PB6) {
        int e = (bid - PB5) * 256 + t;
        int k = e >> 8, n = e & 255;
        outWt[(size_t)n * 256 + k] = f2bf(outW[(size_t)k * 256 + n]);
    } else {
        int blk = bid - PB6;  // v*4 + l
        int v = blk >> 2, l = blk & 3;
        float acc = vB[t];
        for (int d = 0; d < ND; ++d)
            acc += (ve[v * ND + d] + le[l * ND + d]) * vW[d * ND + t];
        emb_proj[blk * ND + t] = acc;
    }
}

// ---------------------------------------------------------------------------
// K_gemms (flat 848 blocks, XCD-chunk swizzled): unified bf16 MFMA GEMM.
//   lb in [0,698): value = featT @ vWt^T + emb_proj -> bf16
//   lb in [698,848): [off|aw] = bevh @ oaWt^T + bias
// BM=128 x BN=128, BK=64, 4 waves (2x2), 4x4 frags, LDS pad-72 (2-way free).
// A and B both [*][256] bf16 row-major: staging is 4x16B coalesced per thread.
// ---------------------------------------------------------------------------
__global__ __launch_bounds__(256) void k_gemms(
        const unsigned short* __restrict__ featT,
        const unsigned short* __restrict__ vWt, const float* __restrict__ emb_proj,
        unsigned short* __restrict__ value,
        const unsigned short* __restrict__ bevh,
        const unsigned short* __restrict__ oaWt,
        const float* __restrict__ oB, const float* __restrict__ aB,
        float* __restrict__ off, float* __restrict__ aw_pre) {
    __shared__ unsigned short As[128][72];
    __shared__ unsigned short Bs[128][72];
    int b = blockIdx.x;
    int lb = (b & 7) * GCHUNK + (b >> 3);
    int t = threadIdx.x;
    int lane = t & 63, w = t >> 6;
    int wm = w >> 1, wn = w & 1;
    int lr = lane & 15, lk = lane >> 4;

    bool isval = lb < VBLKS;
    int m0, c0;
    const unsigned short *ap, *bp;
    if (isval) {
        m0 = (lb >> 1) * 128; c0 = (lb & 1) * 128;
        ap = featT; bp = vWt;
    } else {
        int r6 = lb - VBLKS;               // 50 x 3
        m0 = (r6 / 3) * 128; c0 = (r6 % 3) * 128;
        ap = bevh; bp = oaWt;
    }
    int sr = t >> 1, sk = (t & 1) * 32;
    const unsigned short* arow = ap + (size_t)(m0 + sr) * 256 + sk;
    const unsigned short* brow = bp + (size_t)(c0 + sr) * 256 + sk;

    fx4 acc[4][4];
#pragma unroll
    for (int i = 0; i < 4; ++i)
#pragma unroll
        for (int j = 0; j < 4; ++j) acc[i][j] = (fx4)0.0f;

    for (int k0 = 0; k0 < 256; k0 += 64) {
        bfx8 a0 = *(const bfx8*)(arow + k0);
        bfx8 a1 = *(const bfx8*)(arow + k0 + 8);
        bfx8 a2 = *(const bfx8*)(arow + k0 + 16);
        bfx8 a3 = *(const bfx8*)(arow + k0 + 24);
        bfx8 b0 = *(const bfx8*)(brow + k0);
        bfx8 b1 = *(const bfx8*)(brow + k0 + 8);
        bfx8 b2 = *(const bfx8*)(brow + k0 + 16);
        bfx8 b3 = *(const bfx8*)(brow + k0 + 24);
        *(bfx8*)&As[sr][sk]      = a0;
        *(bfx8*)&As[sr][sk + 8]  = a1;
        *(bfx8*)&As[sr][sk + 16] = a2;
        *(bfx8*)&As[sr][sk + 24] = a3;
        *(bfx8*)&Bs[sr][sk]      = b0;
        *(bfx8*)&Bs[sr][sk + 8]  = b1;
        *(bfx8*)&Bs[sr][sk + 16] = b2;
        *(bfx8*)&Bs[sr][sk + 24] = b3;
        __syncthreads();
#pragma unroll
        for (int ks = 0; ks < 64; ks += 32) {
            bfx8 af[4], bf[4];
#pragma unroll
            for (int f = 0; f < 4; ++f) {
                af[f] = *(bfx8*)&As[wm * 64 + f * 16 + lr][ks + lk * 8];
                bf[f] = *(bfx8*)&Bs[wn * 64 + f * 16 + lr][ks + lk * 8];
            }
#pragma unroll
            for (int fm = 0; fm < 4; ++fm)
#pragma unroll
                for (int fn = 0; fn < 4; ++fn)
                    acc[fm][fn] = __builtin_amdgcn_mfma_f32_16x16x32_bf16(
                        af[fm], bf[fn], acc[fm][fn], 0, 0, 0);
        }
        __syncthreads();
    }

    if (isval) {
#pragma unroll
        for (int fm = 0; fm < 4; ++fm) {
#pragma unroll
            for (int r = 0; r < 4; ++r) {
                int m = m0 + wm * 64 + fm * 16 + lk * 4 + r;
                if (m >= MROWS) continue;
                int v = m / NTOK;
                int n = m - v * NTOK;
                int l = (n < 5600) ? 0 : (n < 7000) ? 1 : (n < 7350) ? 2 : 3;
                const float* ep = emb_proj + (size_t)(v * 4 + l) * ND;
#pragma unroll
                for (int fn = 0; fn < 4; ++fn) {
                    int col = c0 + wn * 64 + fn * 16 + lr;
                    value[(size_t)m * ND + col] = f2bf(acc[fm][fn][r] + ep[col]);
                }
            }
        }
    } else if (c0 < 256) {
#pragma unroll
        for (int fm = 0; fm < 4; ++fm) {
#pragma unroll
            for (int fn = 0; fn < 4; ++fn) {
                int col = c0 + wn * 64 + fn * 16 + lr;
                float bs = oB[col];
#pragma unroll
                for (int r = 0; r < 4; ++r) {
                    int m = m0 + wm * 64 + fm * 16 + lk * 4 + r;
                    off[(size_t)m * 256 + col] = acc[fm][fn][r] + bs;
                }
            }
        }
    } else {
#pragma unroll
        for (int fm = 0; fm < 4; ++fm) {
#pragma unroll
            for (int fn = 0; fn < 4; ++fn) {
                int col = wn * 64 + fn * 16 + lr;  // 0..127 within aw
                float bs = aB[col];
#pragma unroll
                for (int r = 0; r < 4; ++r) {
                    int m = m0 + wm * 64 + fm * 16 + lk * 4 + r;
                    aw_pre[(size_t)m * 128 + col] = acc[fm][fn][r] + bs;
                }
            }
        }
    }
}

// ---------------------------------------------------------------------------
// K_sample: 2 queries/block (thread = qq x channel-pair). Prologue: softmax +
// per-(q,v,combo) clamped token indices (ushort4) & aw-premultiplied bilinear
// weights (half4) into LDS. Main loop per (v,combo): 2 x 8B LDS broadcast +
// 4 coalesced dword loads + 8 FMA. XCD-chunked block swizzle.
// ---------------------------------------------------------------------------
#define SQB 2
__global__ __launch_bounds__(256) void k_sample(
        const float2* __restrict__ coords, const int* __restrict__ mask,
        const float* __restrict__ off, const float* __restrict__ awlog,
        const unsigned short* __restrict__ value, float* __restrict__ slots) {
    __shared__ float aw_s[SQB][128];
    __shared__ unsigned short lin_s[SQB][NV][128][4];
    __shared__ _Float16 w_s[SQB][NV][128][4];
    __shared__ float2 cxy_s[SQB][NV];
    __shared__ int msk_s[SQB][NV];

    int b = blockIdx.x;                       // 3200, % 8 == 0
    int lb = (b & 7) * (NQ / SQB / 8) + (b >> 3);
    int q0 = lb * SQB;
    int t = threadIdx.x;
    if (t < SQB * NV) {
        int qq = t / NV, v = t - qq * NV;
        msk_s[qq][v] = mask[v * NQ + q0 + qq];
        cxy_s[qq][v] = coords[v * NQ + q0 + qq];
    }
    {
        int qq = t >> 7, c2 = t & 127;
        aw_s[qq][c2] = awlog[(size_t)(q0 + qq) * 128 + c2];
    }
    __syncthreads();
    if (t < SQB * NHEAD) {
        int qq = t >> 3, h = t & 7;
        float* p = &aw_s[qq][h * 16];
        float mx = p[0];
#pragma unroll
        for (int i = 1; i < 16; ++i) mx = fmaxf(mx, p[i]);
        float e[16];
        float s = 0.0f;
#pragma unroll
        for (int i = 0; i < 16; ++i) { e[i] = __expf(p[i] - mx); s += e[i]; }
        float inv = 1.0f / s;
#pragma unroll
        for (int i = 0; i < 16; ++i) p[i] = e[i] * inv;
    }
    __syncthreads();

    const int LW[4] = {100, 50, 25, 13};
    const int LH[4] = {56, 28, 14, 7};
    const int LST[4] = {0, 5600, 7000, 7350};
    for (int idx = t; idx < SQB * NV * 128; idx += 256) {
        int c2 = idx & 127;
        int rem = idx >> 7;
        int qq = rem / NV, v = rem - qq * NV;
        if (!msk_s[qq][v]) continue;
        int ll = (c2 >> 2) & 3;
        int iwl = LW[ll], ihl = LH[ll], st = LST[ll];
        float wl = (float)iwl, hl = (float)ihl;
        float2 o2 = *(const float2*)&off[(size_t)(q0 + qq) * 256 + 2 * c2];
        float2 cc = cxy_s[qq][v];
        float gx = cc.x * wl + o2.x - 0.5f;
        float gy = cc.y * hl + o2.y - 0.5f;
        float fxf = floorf(gx), fyf = floorf(gy);
        int x0 = (int)fxf, y0 = (int)fyf;
        float wx = gx - fxf, wy = gy - fyf;
        bool bx0 = (unsigned)x0 < (unsigned)iwl;
        bool bx1 = (unsigned)(x0 + 1) < (unsigned)iwl;
        bool by0 = (unsigned)y0 < (unsigned)ihl;
        bool by1 = (unsigned)(y0 + 1) < (unsigned)ihl;
        int cx0 = min(max(x0, 0), iwl - 1);
        int cx1 = min(max(x0 + 1, 0), iwl - 1);
        int cy0 = min(max(y0, 0), ihl - 1);
        int cy1 = min(max(y0 + 1, 0), ihl - 1);
        float wa = aw_s[qq][c2];
        int r0 = st + cy0 * iwl, r1 = st + cy1 * iwl;
        usx4 lin;
        lin.x = (unsigned short)(r0 + cx0);
        lin.y = (unsigned short)(r0 + cx1);
        lin.z = (unsigned short)(r1 + cx0);
        lin.w = (unsigned short)(r1 + cx1);
        hx4 ww;
        ww.x = (_Float16)((bx0 && by0) ? (1.0f - wx) * (1.0f - wy) * wa : 0.0f);
        ww.y = (_Float16)((bx1 && by0) ? wx * (1.0f - wy) * wa : 0.0f);
        ww.z = (_Float16)((bx0 && by1) ? (1.0f - wx) * wy * wa : 0.0f);
        ww.w = (_Float16)((bx1 && by1) ? wx * wy * wa : 0.0f);
        *(usx4*)lin_s[qq][v][c2] = lin;
        *(hx4*)w_s[qq][v][c2] = ww;
    }
    __syncthreads();

    int qq = t >> 7, cp = t & 127;
    int hb = (cp >> 4) * 16;
    float acc0 = 0.0f, acc1 = 0.0f;
    int cnt = 0;
#pragma unroll
    for (int v = 0; v < NV; ++v) cnt += msk_s[qq][v];
    for (int v = 0; v < NV; ++v) {
        if (!msk_s[qq][v]) continue;
        const uint32_t* vb = (const uint32_t*)(value + (size_t)v * NTOK * 256) + cp;
#pragma unroll
        for (int ci = 0; ci < 16; ++ci) {
            int c2 = hb + ci;
            usx4 lin = *(const usx4*)lin_s[qq][v][c2];
            hx4 wh = *(const hx4*)w_s[qq][v][c2];
            uint32_t u0 = vb[(size_t)lin.x * 128];
            uint32_t u1 = vb[(size_t)lin.y * 128];
            uint32_t u2 = vb[(size_t)lin.z * 128];
            uint32_t u3 = vb[(size_t)lin.w * 128];
            float w0 = (float)wh.x, w1 = (float)wh.y;
            float w2 = (float)wh.z, w3 = (float)wh.w;
            acc0 += w0 * lof(u0) + w1 * lof(u1) + w2 * lof(u2) + w3 * lof(u3);
            acc1 += w0 * hif(u0) + w1 * hif(u1) + w2 * hif(u2) + w3 * hif(u3);
        }
    }
    float invc = 1.0f / fmaxf((float)cnt, 1.0f);
    *(float2*)&slots[(size_t)(q0 + qq) * 256 + 2 * cp] = make_float2(acc0 * invc, acc1 * invc);
}

// ---------------------------------------------------------------------------
// K_out: out = slots @ outWt^T + outB + bev.  BM=64 x BN=128 MFMA tile.
// ---------------------------------------------------------------------------
__global__ __launch_bounds__(256) void k_out(
        const float* __restrict__ A, const unsigned short* __restrict__ Bt,
        const float* __restrict__ bias, const float* __restrict__ addsrc,
        float* __restrict__ out) {
    __shared__ unsigned short As[64][40];
    __shared__ unsigned short Bs[128][40];
    int t = threadIdx.x;
    int m0 = blockIdx.x * 64, c0 = blockIdx.y * 128;
    int lane = t & 63, w = t >> 6;
    int wm = w >> 1, wn = w & 1;
    int lr = lane & 15, lk = lane >> 4;
    int mA = t & 63, kg = t >> 6;
    const float* ap = A + (size_t)(m0 + mA) * 256 + kg * 8;
    const unsigned short* bp = Bt + (size_t)(c0 + (t >> 1)) * 256 + (t & 1) * 16;
    fx4 acc[2][4];
#pragma unroll
    for (int i = 0; i < 2; ++i)
#pragma unroll
        for (int j = 0; j < 4; ++j) acc[i][j] = (fx4)0.0f;
    for (int k0 = 0; k0 < 256; k0 += 32) {
        float va[8];
        *(float4*)&va[0] = *(const float4*)(ap + k0);
        *(float4*)&va[4] = *(const float4*)(ap + k0 + 4);
        bfx8 a8;
#pragma unroll
        for (int i = 0; i < 8; ++i) a8[i] = (short)f2bf(va[i]);
        *(bfx8*)&As[mA][kg * 8] = a8;
        *(bfx8*)&Bs[t >> 1][(t & 1) * 16] = *(const bfx8*)(bp + k0);
        *(bfx8*)&Bs[t >> 1][(t & 1) * 16 + 8] = *(const bfx8*)(bp + k0 + 8);
        __syncthreads();
        bfx8 af[2], bf[4];
#pragma unroll
        for (int f = 0; f < 2; ++f)
            af[f] = *(bfx8*)&As[wm * 32 + f * 16 + lr][lk * 8];
#pragma unroll
        for (int f = 0; f < 4; ++f)
            bf[f] = *(bfx8*)&Bs[wn * 64 + f * 16 + lr][lk * 8];
#pragma unroll
        for (int fm = 0; fm < 2; ++fm)
#pragma unroll
            for (int fn = 0; fn < 4; ++fn)
                acc[fm][fn] = __builtin_amdgcn_mfma_f32_16x16x32_bf16(
                    af[fm], bf[fn], acc[fm][fn], 0, 0, 0);
        __syncthreads();
    }
#pragma unroll
    for (int fm = 0; fm < 2; ++fm) {
#pragma unroll
        for (int fn = 0; fn < 4; ++fn) {
            int col = c0 + wn * 64 + fn * 16 + lr;
            float bs = bias[col];
#pragma unroll
            for (int r = 0; r < 4; ++r) {
                int m = m0 + wm * 32 + fm * 16 + lk * 4 + r;
                out[(size_t)m * 256 + col] =
                    acc[fm][fn][r] + bs + addsrc[(size_t)m * 256 + col];
            }
        }
    }
}

// ---------------------------------------------------------------------------
extern "C" void kernel_launch(void* const* d_in, const int* in_sizes, int n_in,
                              void* d_out, int out_size, void* d_ws, size_t ws_size,
                              hipStream_t stream) {
    const float* f0   = (const float*)d_in[0];
    const float* f1   = (const float*)d_in[1];
    const float* f2   = (const float*)d_in[2];
    const float* f3   = (const float*)d_in[3];
    const float* l2i  = (const float*)d_in[4];
    const float* bev  = (const float*)d_in[5];
    const float* le   = (const float*)d_in[6];
    const float* ve   = (const float*)d_in[7];
    const float* vW   = (const float*)d_in[8];
    const float* vB   = (const float*)d_in[9];
    const float* oW   = (const float*)d_in[10];
    const float* oB   = (const float*)d_in[11];
    const float* aW   = (const float*)d_in[12];
    const float* aB   = (const float*)d_in[13];
    const float* outW = (const float*)d_in[14];
    const float* outB = (const float*)d_in[15];
    float* out = (float*)d_out;

    char* ws = (char*)d_ws;
    size_t o = 0;
    auto alloc = [&](size_t bytes) {
        void* p = ws + o;
        o += (bytes + 255) & ~(size_t)255;
        return p;
    };
    float2* coords   = (float2*)alloc((size_t)NV * NQ * sizeof(float2));
    int*    mask     = (int*)alloc((size_t)NV * NQ * sizeof(int));
    float*  emb_proj = (float*)alloc((size_t)24 * ND * sizeof(float));
    float*  off      = (float*)alloc((size_t)NQ * 256 * sizeof(float));
    float*  aw_pre   = (float*)alloc((size_t)NQ * 128 * sizeof(float));
    float*  slots    = (float*)alloc((size_t)NQ * 256 * sizeof(float));
    unsigned short* value = (unsigned short*)alloc((size_t)MROWS * ND * sizeof(short));
    unsigned short* featT = (unsigned short*)alloc((size_t)MROWSP * ND * sizeof(short));
    unsigned short* bevh  = (unsigned short*)alloc((size_t)NQ * ND * sizeof(short));
    unsigned short* vWt   = (unsigned short*)alloc((size_t)256 * 256 * sizeof(short));
    unsigned short* oaWt  = (unsigned short*)alloc((size_t)384 * 256 * sizeof(short));
    unsigned short* outWt = (unsigned short*)alloc((size_t)256 * 256 * sizeof(short));

    k_prep<<<PBT, 256, 0, stream>>>(f0, f1, f2, f3, l2i, bev, ve, le, vW, vB,
                                    oW, aW, outW, coords, mask, featT, bevh,
                                    vWt, oaWt, outWt, emb_proj);
    k_gemms<<<GBLKS, 256, 0, stream>>>(featT, vWt, emb_proj, value,
                                       bevh, oaWt, oB, aB, off, aw_pre);
    k_sample<<<NQ / SQB, 256, 0, stream>>>(coords, mask, off, aw_pre, value, slots);
    dim3 gout(NQ / 64, 2);
    k_out<<<gout, 256, 0, stream>>>(slots, outWt, outB, bev, out);
}